// Round 3
// baseline (56.176 us; speedup 1.0000x reference)
//
#include <hip/hip_runtime.h>
#include <math.h>

// MixedFeatureEmbedder: out[b, f, :] for f even = x[b,f]*W_num[f/2,:] + b_num[f/2,:]
//                       for f odd  = emb_tables[f/2, clip(rint(nan_to_num(x[b,f])),0,99), :]
// Shapes: x (8192,64) f32, W_num/b_num (32,128) f32, emb_tables (32,100,128) f32,
// out (8192,64,128) f32 = 256 MiB -> write-BW bound.
//
// R2 changes vs R1 (54.4 us, neutral):
//  - group -> (feature, batch-slice) remap: each 32-lane group owns ONE fixed feature;
//    both groups of a wave share parity -> branch is wave-uniform (was divergent every iter)
//  - W/b fragment loads hoisted out of the loop (loop-invariant per group)
//  - #pragma unroll 4: 4 independent gathers/stores in flight per group

#define TOKEN_DIM 128
#define N_FEAT 64
#define CARD 100

typedef float f32x4 __attribute__((ext_vector_type(4)));

// grid = 2048 blocks x 256 threads = 16384 groups of 32 lanes.
// gid bits: [4:0] = f/2, [5] = parity, [13:6] = b0 (0..255). b stride = 256.
__global__ __launch_bounds__(256) void mixed_embed_kernel(
    const float* __restrict__ x,
    const f32x4* __restrict__ W_num,
    const f32x4* __restrict__ b_num,
    const f32x4* __restrict__ emb,
    f32x4* __restrict__ out,
    int batch)
{
    const int lane = threadIdx.x & 31;
    const int gid  = blockIdx.x * 8 + (threadIdx.x >> 5);
    const int f2   = gid & 31;                 // feature pair index
    const int par  = (gid >> 5) & 1;           // 0 = numeric (even f), 1 = categorical (odd f)
    const int f    = 2 * f2 + par;
    const int b0   = gid >> 6;                 // [0, 256)
    const int bstr = (gridDim.x * 8) >> 6;     // 256

    if (par == 0) {
        // numeric feature: r = x * W + b, W/b loop-invariant
        const f32x4 w  = W_num[f2 * (TOKEN_DIM/4) + lane];
        const f32x4 bb = b_num[f2 * (TOKEN_DIM/4) + lane];
        #pragma unroll 4
        for (int b = b0; b < batch; b += bstr) {
            const float xv = x[b * N_FEAT + f];
            f32x4 r;
            r.x = fmaf(xv, w.x, bb.x);
            r.y = fmaf(xv, w.y, bb.y);
            r.z = fmaf(xv, w.z, bb.z);
            r.w = fmaf(xv, w.w, bb.w);
            __builtin_nontemporal_store(r, out + (b * N_FEAT + f) * (TOKEN_DIM/4) + lane);
        }
    } else {
        // categorical feature: embedding gather from this feature's table
        const f32x4* __restrict__ table = emb + f2 * (CARD * (TOKEN_DIM/4));
        #pragma unroll 4
        for (int b = b0; b < batch; b += bstr) {
            const float xv = x[b * N_FEAT + f];
            float xc = isnan(xv) ? 0.0f : xv;
            float ridx = rintf(xc);                             // round half-even = jnp.round
            ridx = fminf(fmaxf(ridx, 0.0f), (float)(CARD - 1));
            const int idx = (int)ridx;
            const f32x4 r = table[idx * (TOKEN_DIM/4) + lane];
            __builtin_nontemporal_store(r, out + (b * N_FEAT + f) * (TOKEN_DIM/4) + lane);
        }
    }
}

extern "C" void kernel_launch(void* const* d_in, const int* in_sizes, int n_in,
                              void* d_out, int out_size, void* d_ws, size_t ws_size,
                              hipStream_t stream) {
    const float* x     = (const float*)d_in[0];
    const f32x4* W_num = (const f32x4*)d_in[1];
    const f32x4* b_num = (const f32x4*)d_in[2];
    const f32x4* emb   = (const f32x4*)d_in[3];
    f32x4* out = (f32x4*)d_out;

    const int batch = in_sizes[0] / N_FEAT;   // 8192

    // 2048 blocks * 8 groups = 16384 groups = 64 features x 256 batch-slices
    mixed_embed_kernel<<<2048, 256, 0, stream>>>(x, W_num, b_num, emb, out, batch);
}

// Round 4
// 43.359 us; speedup vs baseline: 1.2956x; 1.2956x over previous
//
#include <hip/hip_runtime.h>
#include <math.h>

// MixedFeatureEmbedder: out[b, f, :] for f even = x[b,f]*W_num[f/2,:] + b_num[f/2,:]
//                       for f odd  = emb_tables[f/2, clip(rint(nan_to_num(x[b,f])),0,99), :]
// Shapes: x (8192,64) f32, W_num/b_num (32,128) f32, emb_tables (32,100,128) f32,
// out (8192,64,128) f32 = 256 MiB -> write-BW bound.
//
// R3: revert to R0's mapping (measured best, 54.05 us): one 32-lane group per output
// row, consecutive groups -> consecutive rows, so each wave stores 1024B contiguous.
// Keep nontemporal stores (neutral perf, protects L2-resident emb tables).
// Floor analysis: 268 MB writes + ~20 MB reads @ 6.9 TB/s (fill-kernel calibrated)
// = ~41 us + ~10-13 us graph-launch/ramp overhead = the ~54 us we measure.

#define TOKEN_DIM 128
#define N_FEAT 64
#define CARD 100

typedef float f32x4 __attribute__((ext_vector_type(4)));

__global__ __launch_bounds__(256) void mixed_embed_kernel(
    const float* __restrict__ x,
    const f32x4* __restrict__ W_num,
    const f32x4* __restrict__ b_num,
    const f32x4* __restrict__ emb,
    f32x4* __restrict__ out,
    int n_rows)
{
    const int row  = blockIdx.x * 8 + (threadIdx.x >> 5);
    const int lane = threadIdx.x & 31;
    if (row >= n_rows) return;

    const int f  = row & (N_FEAT - 1);   // feature index (x is [BATCH][64], row = b*64+f)
    const int f2 = f >> 1;

    const float xv = x[row];

    f32x4 r;
    if ((f & 1) == 0) {
        // numeric: out = x * W + b
        const f32x4 w  = W_num[f2 * (TOKEN_DIM/4) + lane];
        const f32x4 bb = b_num[f2 * (TOKEN_DIM/4) + lane];
        r.x = fmaf(xv, w.x, bb.x);
        r.y = fmaf(xv, w.y, bb.y);
        r.z = fmaf(xv, w.z, bb.z);
        r.w = fmaf(xv, w.w, bb.w);
    } else {
        // categorical: embedding gather
        float xc = isnan(xv) ? 0.0f : xv;
        float ridx = rintf(xc);                              // round half-even = jnp.round
        ridx = fminf(fmaxf(ridx, 0.0f), (float)(CARD - 1));
        const int idx = (int)ridx;
        r = emb[(f2 * CARD + idx) * (TOKEN_DIM/4) + lane];
    }

    __builtin_nontemporal_store(r, out + row * (TOKEN_DIM/4) + lane);
}

extern "C" void kernel_launch(void* const* d_in, const int* in_sizes, int n_in,
                              void* d_out, int out_size, void* d_ws, size_t ws_size,
                              hipStream_t stream) {
    const float* x     = (const float*)d_in[0];
    const f32x4* W_num = (const f32x4*)d_in[1];
    const f32x4* b_num = (const f32x4*)d_in[2];
    const f32x4* emb   = (const f32x4*)d_in[3];
    f32x4* out = (f32x4*)d_out;

    const int batch  = in_sizes[0] / N_FEAT;      // 8192
    const int n_rows = batch * N_FEAT;            // 524288
    const int blocks = (n_rows + 7) / 8;          // 8 rows (one wave = 2 rows) per block

    mixed_embed_kernel<<<blocks, 256, 0, stream>>>(x, W_num, b_num, emb, out, n_rows);
}